// Round 12
// baseline (161.503 us; speedup 1.0000x reference)
//
#include <hip/hip_runtime.h>
#include <hip/hip_bf16.h>

typedef __attribute__((ext_vector_type(2)))  float f32x2;
typedef __attribute__((ext_vector_type(4)))  float f32x4;
typedef __attribute__((ext_vector_type(8)))  short bf16x8;
typedef __attribute__((ext_vector_type(4)))  unsigned int u32x4;

__device__ __forceinline__ short f2bf(float x){
    __hip_bfloat16 h = __float2bfloat16(x);
    return __builtin_bit_cast(short, h);
}
__device__ __forceinline__ float bf2f(short x){
    unsigned int u = ((unsigned int)(unsigned short)x) << 16;
    return __builtin_bit_cast(float, u);
}
// one packed RNE convert for a bf16 pair (hw v_cvt_pk_bf16_f32)
__device__ __forceinline__ unsigned int cvt2(float lo, float hi){
    unsigned int r;
    asm("v_cvt_pk_bf16_f32 %0, %1, %2" : "=v"(r) : "v"(lo), "v"(hi));
    return r;
}

// ---------------------------------------------------------------- prep: weight prep + Aq (r10 verbatim)
// blocks 0..71  : W1t bf16 tiling of W1a/W1b in 16x16x32 B-frag chunk order (prologue GEMM)
// blocks 72..75 : W2t = W2 bf16 pre-tiled in 16x16x32 B-frag chunk order for main:
//                 chunk c = (s*12 + t)*64 + lane; W2t[c*8+j] = bf16(W2[k][n]),
//                 k = s*32 + ((lane>>4)&3)*8 + j,  n = t*16 + (lane&15)   (s<12, t<12)
// block  76     : W1cdf f32 [768]: [0..383]=W1[768][:], [384..767]=W1[769][:]
// blocks 77..124: Aq(f32) 16x16 output tiles (48 blocks, 1 wave, 12 MFMA each)
__global__ __launch_bounds__(256)
void prep_kernel(const float* __restrict__ query, const float* __restrict__ W1,
                 const float* __restrict__ b1, const float* __restrict__ W2,
                 short* __restrict__ W1t, float* __restrict__ W1cdf,
                 short* __restrict__ W2t, float* __restrict__ Aq){
    const int b = blockIdx.x, tid = threadIdx.x;

    if (b < 72){
        // W1 tiling: 576 chunks x 64 lanes = 36864 lane-tasks; 72 blocks x 256 thr x 2 tasks
        const int lt0 = b*256 + tid;
        #pragma unroll
        for (int i=0;i<2;i++){
            const int lt    = lt0 + i*18432;
            const int chunk = lt >> 6, lane = lt & 63;
            const int cl = lane & 15, quad = lane >> 4;
            const int half = (chunk >= 288) ? 1 : 0;
            const int cs = chunk - half*288;
            const int s = cs/24, ct = cs%24;
            const float* src = W1 + (half*384 + s*32 + quad*8)*384 + ct*16 + cl;
            float v[8];
            #pragma unroll
            for (int j=0;j<8;j++) v[j] = src[j*384];
            u32x4 o;
            o[0] = cvt2(v[0],v[1]); o[1] = cvt2(v[2],v[3]);
            o[2] = cvt2(v[4],v[5]); o[3] = cvt2(v[6],v[7]);
            *(u32x4*)(W1t + chunk*512 + lane*8) = o;
        }
    } else if (b < 76){
        // W2 bf16 tiling for main's 16x16x32 B-frags
        const int t0 = (b - 72)*256 + tid;
        #pragma unroll
        for (int i=0;i<9;i++){
            int c = t0 + i*1024;                     // < 9216
            int lane_c = c & 63, st = c >> 6;        // st < 144
            int s = st/12, t2 = st%12;
            int n = t2*16 + (lane_c&15), kb = s*32 + ((lane_c>>4)&3)*8;
            bf16x8 v;
            #pragma unroll
            for (int j=0;j<8;j++) v[j] = f2bf(W2[(kb+j)*192 + n]);
            *(bf16x8*)(W2t + c*8) = v;
        }
    } else if (b == 76){
        #pragma unroll
        for (int i=0;i<3;i++){
            int o = tid + i*256;                     // < 768
            W1cdf[o] = (o < 384) ? W1[768*384 + o] : W1[769*384 + (o - 384)];
        }
    } else {
        // Aq 16x16 tile (single wave; pre1-verified fragment pattern)
        if (tid < 64){
            const int aq = b - 77;                   // 0..47
            const int mt = aq / 24, nt = aq % 24;
            const int lane = tid;
            const int cl = lane & 15, quad = lane >> 4;

            f32x4 acc = (f32x4){0.f,0.f,0.f,0.f};
            #pragma unroll 1
            for (int s=0;s<12;s++){
                const float* ap = query + (mt*16+cl)*384 + s*32 + quad*8;
                const f32x4 a0 = *(const f32x4*)ap;
                const f32x4 a1 = *(const f32x4*)(ap+4);
                u32x4 ua;
                ua[0] = cvt2(a0[0],a0[1]); ua[1] = cvt2(a0[2],a0[3]);
                ua[2] = cvt2(a1[0],a1[1]); ua[3] = cvt2(a1[2],a1[3]);
                const bf16x8 af = __builtin_bit_cast(bf16x8, ua);
                const float* wk = W1 + (s*32 + quad*8)*384 + nt*16 + cl;
                bf16x8 bfv;
                #pragma unroll
                for (int j=0;j<8;j++) bfv[j] = f2bf(wk[j*384]);
                acc = __builtin_amdgcn_mfma_f32_16x16x32_bf16(af, bfv, acc, 0, 0, 0);
            }
            const int col = nt*16 + cl;
            const float b1v = b1[col];
            #pragma unroll
            for (int r=0;r<4;r++)
                Aq[(mt*16 + quad*4 + r)*384 + col] = acc[r] + b1v;
        }
    }
}

// ---------------------------------------------------------------- main fused: r10 prologue + 2-column MLP
// 256 blocks x 1024 thr = 16 waves = 4 waves/SIMD, 1 block/CU (LDS 162,816 B).
// Prologue (r6/r10 VERBATIM, passed): waves 0..3 Bws GEMM + dense; waves 4..15 staging.
// MLP (r11 change): the two t4 passes FUSED -- each wave sweeps K once, processing BOTH of
// its doc columns (dcolA = r0+colslot, dcolB = +8) with frA/frB sharing every W2 frag read:
// frag reads 4608 -> 2304 per CU (the measured dominant LDS issue load), loop overhead halves,
// fr-build total unchanged (no r9-style duplication). acc doubles to 96 VGPRs; bw/Aq prefetch
// slots dropped (bw is LDS; Aq is L2-resident, hidden by 4 waves/SIMD) to stay <=128 regs.
// A-frag: m=lane&15, k=(lane>>4)*8+j.  B-frag: n=lane&15, same k.
// C/D: col=lane&15, row=(lane>>4)*4+reg  [m89/m91-verified].
__global__ __launch_bounds__(1024)
void main_kernel(const float* __restrict__ doc, const float* __restrict__ query,
                 const float* __restrict__ Aq, const short* __restrict__ W1t,
                 const float* __restrict__ W1cdf, const short* __restrict__ W2t,
                 const float* __restrict__ b2, const float* __restrict__ W3,
                 const float* __restrict__ b3, const float* __restrict__ sparse,
                 float* __restrict__ out_dense, float* __restrict__ out_sparse,
                 float* __restrict__ out_final){
    __shared__ __align__(16) short lw[73728];        // 147,456 B  W2 bf16 (16x16x32 frag order)
    __shared__ __align__(16) short lbw[6144];        //  12,288 B  Bws slice [16 docs][384] bf16
    __shared__ __align__(16) float lcd[768];         //   3,072 B  [0..383]=W1c, [384..767]=W1d
    const int tid = threadIdx.x, bb = blockIdx.x;
    const int r0 = bb*16;
    const int lane = tid & 63, w = tid >> 6;

    if (w < 4){
        // ---- Bws GEMM + dense for this block's 16 docs (pre1-verified, inline f32->bf16)
        const int cl = lane & 15, quad = lane >> 4, tq = w & 1;
        const float* ap = doc + (r0+cl)*384 + quad*8;
        const float* qp = query + (tq*16 + cl)*384 + quad*8;
        const short* wp = W1t + 147456 + (w*6)*512 + lane*8;   // W1b half

        f32x4 acc[6];
        #pragma unroll
        for (int t=0;t<6;t++) acc[t] = (f32x4){0.f,0.f,0.f,0.f};
        f32x4 accd = (f32x4){0.f,0.f,0.f,0.f};

        f32x4 a0c = *(const f32x4*)(ap),  a1c = *(const f32x4*)(ap+4);
        f32x4 q0c = *(const f32x4*)(qp),  q1c = *(const f32x4*)(qp+4);
        bf16x8 b_c[6];
        #pragma unroll
        for (int tt=0;tt<6;tt++) b_c[tt] = *(const bf16x8*)(wp + tt*512);

        #pragma unroll 1
        for (int s=0;s<12;s++){
            const int sn = (s < 11) ? s+1 : 0;       // dummy wrap on last iter
            const f32x4 a0n = *(const f32x4*)(ap + sn*32);
            const f32x4 a1n = *(const f32x4*)(ap + sn*32 + 4);
            const f32x4 q0n = *(const f32x4*)(qp + sn*32);
            const f32x4 q1n = *(const f32x4*)(qp + sn*32 + 4);
            bf16x8 b_n[6];
            #pragma unroll
            for (int tt=0;tt<6;tt++) b_n[tt] = *(const bf16x8*)(wp + sn*12288 + tt*512);

            u32x4 ua, uq;
            ua[0] = cvt2(a0c[0],a0c[1]); ua[1] = cvt2(a0c[2],a0c[3]);
            ua[2] = cvt2(a1c[0],a1c[1]); ua[3] = cvt2(a1c[2],a1c[3]);
            uq[0] = cvt2(q0c[0],q0c[1]); uq[1] = cvt2(q0c[2],q0c[3]);
            uq[2] = cvt2(q1c[0],q1c[1]); uq[3] = cvt2(q1c[2],q1c[3]);
            const bf16x8 af = __builtin_bit_cast(bf16x8, ua);
            const bf16x8 qf = __builtin_bit_cast(bf16x8, uq);

            #pragma unroll
            for (int tt=0;tt<6;tt++)
                acc[tt] = __builtin_amdgcn_mfma_f32_16x16x32_bf16(af, b_c[tt], acc[tt], 0, 0, 0);
            accd = __builtin_amdgcn_mfma_f32_16x16x32_bf16(af, qf, accd, 0, 0, 0);

            a0c = a0n; a1c = a1n; q0c = q0n; q1c = q1n;
            #pragma unroll
            for (int tt=0;tt<6;tt++) b_c[tt] = b_n[tt];
        }

        // Bws slice -> LDS: doc_local = quad*4+r, col = (w*6+tt)*16+cl
        #pragma unroll
        for (int tt=0;tt<6;tt++){
            const int col = (w*6+tt)*16 + cl;
            #pragma unroll
            for (int r=0;r<4;r++)
                lbw[(quad*4 + r)*384 + col] = f2bf(acc[tt][r]);
        }
        // dense store (waves 0,1 only; waves 2,3 computed duplicates for uniformity)
        if (w < 2){
            #pragma unroll
            for (int r=0;r<4;r++)
                out_dense[(tq*16 + cl)*4096 + r0 + quad*4 + r] = accd[r];
        }
    } else {
        // ---- staging: lw (waves 4..15, 12 chunks each), lcd, sparse copy
        #pragma unroll
        for (int i=0;i<12;i++){
            const int c = (w-4)*64 + lane + i*768;   // < 9216
            *(f32x4*)(lw + c*8) = *(const f32x4*)(W2t + c*8);
        }
        if (tid >= 256 && tid < 448){
            const int t = tid - 256;
            *(f32x4*)(lcd + t*4) = *(const f32x4*)(W1cdf + t*4);
        }
        if (tid >= 512 && tid < 640){
            const int idx = tid - 512;
            const int qq = idx >> 2, c4 = idx & 3;
            *(f32x4*)(out_sparse + qq*4096 + r0 + c4*4) =
                *(const f32x4*)(sparse + qq*4096 + r0 + c4*4);
        }
    }
    __syncthreads();    // drains vmcnt -> dense stores visible via L2; LDS complete

    // ---- MLP: 2-column fused K-sweep (m-split, 16x16x32)
    const int colslot = w >> 1, mhalf = w & 1;
    const int cl = lane & 15, g = lane >> 4;
    const int mrow = mhalf*16 + cl;                  // q-row of this lane's A-frag
    const int k8 = g*8;                              // k-offset within a K=32 step
    const float b3v = b3[0];
    const int dcolA = r0 + colslot, dcolB = dcolA + 8;

    const float dsvA = out_dense[mrow*4096 + dcolA];
    const float ssvA = sparse[mrow*4096 + dcolA];
    const float dsvB = out_dense[mrow*4096 + dcolB];
    const float ssvB = sparse[mrow*4096 + dcolB];

    f32x4 accA[12], accB[12];
    #pragma unroll
    for (int t=0;t<12;t++){
        accA[t] = (f32x4){0.f,0.f,0.f,0.f};
        accB[t] = (f32x4){0.f,0.f,0.f,0.f};
    }

    const short* bpA = lbw + colslot*384;
    const short* bpB = lbw + (colslot+8)*384;
    const float* ap  = Aq + mrow*384;

    #pragma unroll 1
    for (int s=0; s<12; s++){
        const int kf = s*32 + k8;
        const f32x4 aC0 = *(const f32x4*)(ap + kf);
        const f32x4 aC1 = *(const f32x4*)(ap + kf + 4);
        const bf16x8 bwA = *(const bf16x8*)(bpA + kf);
        const bf16x8 bwB = *(const bf16x8*)(bpB + kf);

        const f32x4 wcA = *(const f32x4*)(lcd + kf);
        const f32x4 wcB = *(const f32x4*)(lcd + kf + 4);
        const f32x4 wdA = *(const f32x4*)(lcd + 384 + kf);
        const f32x4 wdB = *(const f32x4*)(lcd + 384 + kf + 4);

        u32x4 fwA, fwB;
        #pragma unroll
        for (int jj=0;jj<2;jj++){
            const float w0 = wcA[jj*2],   w1 = wcA[jj*2+1];
            const float d0 = wdA[jj*2],   d1 = wdA[jj*2+1];
            const float a0 = aC0[jj*2],   a1 = aC0[jj*2+1];
            const float bA0 = bf2f(bwA[jj*2]),   bA1 = bf2f(bwA[jj*2+1]);
            const float bB0 = bf2f(bwB[jj*2]),   bB1 = bf2f(bwB[jj*2+1]);
            fwA[jj] = cvt2(fmaxf(a0 + bA0 + dsvA*w0 + ssvA*d0, 0.f),
                           fmaxf(a1 + bA1 + dsvA*w1 + ssvA*d1, 0.f));
            fwB[jj] = cvt2(fmaxf(a0 + bB0 + dsvB*w0 + ssvB*d0, 0.f),
                           fmaxf(a1 + bB1 + dsvB*w1 + ssvB*d1, 0.f));
        }
        #pragma unroll
        for (int jj=0;jj<2;jj++){
            const float w0 = wcB[jj*2],   w1 = wcB[jj*2+1];
            const float d0 = wdB[jj*2],   d1 = wdB[jj*2+1];
            const float a0 = aC1[jj*2],   a1 = aC1[jj*2+1];
            const float bA0 = bf2f(bwA[4+jj*2]), bA1 = bf2f(bwA[4+jj*2+1]);
            const float bB0 = bf2f(bwB[4+jj*2]), bB1 = bf2f(bwB[4+jj*2+1]);
            fwA[2+jj] = cvt2(fmaxf(a0 + bA0 + dsvA*w0 + ssvA*d0, 0.f),
                             fmaxf(a1 + bA1 + dsvA*w1 + ssvA*d1, 0.f));
            fwB[2+jj] = cvt2(fmaxf(a0 + bB0 + dsvB*w0 + ssvB*d0, 0.f),
                             fmaxf(a1 + bB1 + dsvB*w1 + ssvB*d1, 0.f));
        }
        const bf16x8 frA = __builtin_bit_cast(bf16x8, fwA);
        const bf16x8 frB = __builtin_bit_cast(bf16x8, fwB);

        // 12 shared B-frag reads, 24 MFMA (each frag feeds both columns)
        const short* lp = lw + s*6144 + lane*8;      // s*12*512 shorts
        #pragma unroll
        for (int tg=0; tg<4; tg++){
            const bf16x8 f0 = *(const bf16x8*)(lp + (tg*3+0)*512);
            const bf16x8 f1 = *(const bf16x8*)(lp + (tg*3+1)*512);
            const bf16x8 f2 = *(const bf16x8*)(lp + (tg*3+2)*512);
            accA[tg*3+0] = __builtin_amdgcn_mfma_f32_16x16x32_bf16(frA, f0, accA[tg*3+0], 0, 0, 0);
            accB[tg*3+0] = __builtin_amdgcn_mfma_f32_16x16x32_bf16(frB, f0, accB[tg*3+0], 0, 0, 0);
            accA[tg*3+1] = __builtin_amdgcn_mfma_f32_16x16x32_bf16(frA, f1, accA[tg*3+1], 0, 0, 0);
            accB[tg*3+1] = __builtin_amdgcn_mfma_f32_16x16x32_bf16(frB, f1, accB[tg*3+1], 0, 0, 0);
            accA[tg*3+2] = __builtin_amdgcn_mfma_f32_16x16x32_bf16(frA, f2, accA[tg*3+2], 0, 0, 0);
            accB[tg*3+2] = __builtin_amdgcn_mfma_f32_16x16x32_bf16(frB, f2, accB[tg*3+2], 0, 0, 0);
        }
    }

    // ---- layer 3 + blend, column A then column B (r10 epilogue pattern x2)
    #pragma unroll
    for (int cc=0; cc<2; cc++){
        const int dcol = cc ? dcolB : dcolA;
        float p0=0.f, p1=0.f, p2=0.f, p3=0.f;
        #pragma unroll
        for (int t=0;t<12;t++){
            const int n = t*16 + cl;
            const float b2v = b2[n];
            const float w3v = W3[n];
            const f32x4 a = cc ? accB[t] : accA[t];
            p0 += fmaxf(a[0] + b2v, 0.0f) * w3v;
            p1 += fmaxf(a[1] + b2v, 0.0f) * w3v;
            p2 += fmaxf(a[2] + b2v, 0.0f) * w3v;
            p3 += fmaxf(a[3] + b2v, 0.0f) * w3v;
        }
        // reduce over the 16 lanes of this g-group (masks 1..8 stay within the group)
        #pragma unroll
        for (int mask=1; mask<16; mask<<=1){
            p0 += __shfl_xor(p0, mask);
            p1 += __shfl_xor(p1, mask);
            p2 += __shfl_xor(p2, mask);
            p3 += __shfl_xor(p3, mask);
        }
        // lane cl<4 writes row mhalf*16 + g*4 + cl (static cndmask chain)
        float myp = p0;
        myp = (cl==1) ? p1 : myp;
        myp = (cl==2) ? p2 : myp;
        myp = (cl==3) ? p3 : myp;
        if (cl < 4){
            const int row = mhalf*16 + g*4 + cl;
            const float logit = myp + b3v;
            const float wgt = 1.0f/(1.0f + __expf(-logit));
            const float dd = out_dense[row*4096 + dcol];
            const float ss = sparse[row*4096 + dcol];
            out_final[row*4096 + dcol] = wgt*dd + (1.0f - wgt)*ss;
        }
    }
}

// ---------------------------------------------------------------- launch
extern "C" void kernel_launch(void* const* d_in, const int* in_sizes, int n_in,
                              void* d_out, int out_size, void* d_ws, size_t ws_size,
                              hipStream_t stream){
    const float* query  = (const float*)d_in[0];
    const float* doc    = (const float*)d_in[1];
    const float* sparse = (const float*)d_in[2];
    const float* W1     = (const float*)d_in[3];
    const float* b1     = (const float*)d_in[4];
    const float* W2     = (const float*)d_in[5];
    const float* b2     = (const float*)d_in[6];
    const float* W3     = (const float*)d_in[7];
    const float* b3     = (const float*)d_in[8];

    float* out_final  = (float*)d_out;                 // [32,4096]
    float* out_dense  = (float*)d_out + 131072;        // [32,4096]
    float* out_sparse = (float*)d_out + 262144;        // [32,4096]

    // workspace layout (16B-aligned), total 789,504 B
    short* W1t   = (short*)d_ws;                                  //   589,824 B  (bf16 tiled W1a+W1b)
    short* W2t   = (short*)((char*)d_ws + 589824);                //   147,456 B  (bf16 tiled W2)
    float* W1cdf = (float*)((char*)d_ws + 737280);                //     3,072 B  (f32  [768])
    float* Aq    = (float*)((char*)d_ws + 740352);                //    49,152 B  (f32  [32][384])

    hipLaunchKernelGGL(prep_kernel, dim3(125), dim3(256), 0, stream,
                       query, W1, b1, W2, W1t, W1cdf, W2t, Aq);
    hipLaunchKernelGGL(main_kernel, dim3(256), dim3(1024), 0, stream,
                       doc, query, Aq, W1t, W1cdf, W2t, b2, W3, b3, sparse,
                       out_dense, out_sparse, out_final);
}

// Round 13
// 118.723 us; speedup vs baseline: 1.3603x; 1.3603x over previous
//
#include <hip/hip_runtime.h>
#include <hip/hip_bf16.h>

typedef __attribute__((ext_vector_type(2)))  float f32x2;
typedef __attribute__((ext_vector_type(4)))  float f32x4;
typedef __attribute__((ext_vector_type(8)))  short bf16x8;
typedef __attribute__((ext_vector_type(4)))  unsigned int u32x4;

__device__ __forceinline__ short f2bf(float x){
    __hip_bfloat16 h = __float2bfloat16(x);
    return __builtin_bit_cast(short, h);
}
__device__ __forceinline__ float bf2f(short x){
    unsigned int u = ((unsigned int)(unsigned short)x) << 16;
    return __builtin_bit_cast(float, u);
}
// one packed RNE convert for a bf16 pair (hw v_cvt_pk_bf16_f32)
__device__ __forceinline__ unsigned int cvt2(float lo, float hi){
    unsigned int r;
    asm("v_cvt_pk_bf16_f32 %0, %1, %2" : "=v"(r) : "v"(lo), "v"(hi));
    return r;
}

// ---------------------------------------------------------------- prep: weight prep + Aq (r10 verbatim)
// blocks 0..71  : W1t bf16 tiling of W1a/W1b in 16x16x32 B-frag chunk order (prologue GEMM)
// blocks 72..75 : W2t = W2 bf16 pre-tiled in 16x16x32 B-frag chunk order for main:
//                 chunk c = (s*12 + t)*64 + lane; W2t[c*8+j] = bf16(W2[k][n]),
//                 k = s*32 + ((lane>>4)&3)*8 + j,  n = t*16 + (lane&15)   (s<12, t<12)
// block  76     : W1cdf f32 [768]: [0..383]=W1[768][:], [384..767]=W1[769][:]
// blocks 77..124: Aq(f32) 16x16 output tiles (48 blocks, 1 wave, 12 MFMA each)
__global__ __launch_bounds__(256)
void prep_kernel(const float* __restrict__ query, const float* __restrict__ W1,
                 const float* __restrict__ b1, const float* __restrict__ W2,
                 short* __restrict__ W1t, float* __restrict__ W1cdf,
                 short* __restrict__ W2t, float* __restrict__ Aq){
    const int b = blockIdx.x, tid = threadIdx.x;

    if (b < 72){
        // W1 tiling: 576 chunks x 64 lanes = 36864 lane-tasks; 72 blocks x 256 thr x 2 tasks
        const int lt0 = b*256 + tid;
        #pragma unroll
        for (int i=0;i<2;i++){
            const int lt    = lt0 + i*18432;
            const int chunk = lt >> 6, lane = lt & 63;
            const int cl = lane & 15, quad = lane >> 4;
            const int half = (chunk >= 288) ? 1 : 0;
            const int cs = chunk - half*288;
            const int s = cs/24, ct = cs%24;
            const float* src = W1 + (half*384 + s*32 + quad*8)*384 + ct*16 + cl;
            float v[8];
            #pragma unroll
            for (int j=0;j<8;j++) v[j] = src[j*384];
            u32x4 o;
            o[0] = cvt2(v[0],v[1]); o[1] = cvt2(v[2],v[3]);
            o[2] = cvt2(v[4],v[5]); o[3] = cvt2(v[6],v[7]);
            *(u32x4*)(W1t + chunk*512 + lane*8) = o;
        }
    } else if (b < 76){
        // W2 bf16 tiling for main's 16x16x32 B-frags
        const int t0 = (b - 72)*256 + tid;
        #pragma unroll
        for (int i=0;i<9;i++){
            int c = t0 + i*1024;                     // < 9216
            int lane_c = c & 63, st = c >> 6;        // st < 144
            int s = st/12, t2 = st%12;
            int n = t2*16 + (lane_c&15), kb = s*32 + ((lane_c>>4)&3)*8;
            bf16x8 v;
            #pragma unroll
            for (int j=0;j<8;j++) v[j] = f2bf(W2[(kb+j)*192 + n]);
            *(bf16x8*)(W2t + c*8) = v;
        }
    } else if (b == 76){
        #pragma unroll
        for (int i=0;i<3;i++){
            int o = tid + i*256;                     // < 768
            W1cdf[o] = (o < 384) ? W1[768*384 + o] : W1[769*384 + (o - 384)];
        }
    } else {
        // Aq 16x16 tile (single wave; pre1-verified fragment pattern)
        if (tid < 64){
            const int aq = b - 77;                   // 0..47
            const int mt = aq / 24, nt = aq % 24;
            const int lane = tid;
            const int cl = lane & 15, quad = lane >> 4;

            f32x4 acc = (f32x4){0.f,0.f,0.f,0.f};
            #pragma unroll 1
            for (int s=0;s<12;s++){
                const float* ap = query + (mt*16+cl)*384 + s*32 + quad*8;
                const f32x4 a0 = *(const f32x4*)ap;
                const f32x4 a1 = *(const f32x4*)(ap+4);
                u32x4 ua;
                ua[0] = cvt2(a0[0],a0[1]); ua[1] = cvt2(a0[2],a0[3]);
                ua[2] = cvt2(a1[0],a1[1]); ua[3] = cvt2(a1[2],a1[3]);
                const bf16x8 af = __builtin_bit_cast(bf16x8, ua);
                const float* wk = W1 + (s*32 + quad*8)*384 + nt*16 + cl;
                bf16x8 bfv;
                #pragma unroll
                for (int j=0;j<8;j++) bfv[j] = f2bf(wk[j*384]);
                acc = __builtin_amdgcn_mfma_f32_16x16x32_bf16(af, bfv, acc, 0, 0, 0);
            }
            const int col = nt*16 + cl;
            const float b1v = b1[col];
            #pragma unroll
            for (int r=0;r<4;r++)
                Aq[(mt*16 + quad*4 + r)*384 + col] = acc[r] + b1v;
        }
    }
}

// ---------------------------------------------------------------- main fused (r10 VERBATIM -- session best, 119.9us)
// 256 blocks x 1024 thr = 16 waves = 4 waves/SIMD, 1 block/CU (LDS 162,816 B).
// Prologue (block b owns docs r0=16b..16b+15 -- fully block-local):
//   waves 0..3 : Bws slice = doc[16 rows] @ W1b + fused dense MFMA; Bws->lbw (LDS),
//                dense->out_dense (global; read back via L2 post-barrier).
//   waves 4..15: lw staging (W2t linear copy), lcd (192 thr), sparse copy (128 thr).
// MLP: m-split, 16x16x32, 12 n-tiles/wave/step; per-wave fr-build covers only its 16 q rows.
// NOTE (r12 lesson): fusing the two t4 passes (accA+accB = 96 acc regs) SPILLS to scratch at
// 1024 threads -- FETCH 6.2->25.6 GB, WRITE 1.5->210 MB, main 48->95us. Do not re-attempt.
// A-frag: m=lane&15, k=(lane>>4)*8+j.  B-frag: n=lane&15, same k.
// C/D: col=lane&15, row=(lane>>4)*4+reg  [m89/m91-verified].
__global__ __launch_bounds__(1024)
void main_kernel(const float* __restrict__ doc, const float* __restrict__ query,
                 const float* __restrict__ Aq, const short* __restrict__ W1t,
                 const float* __restrict__ W1cdf, const short* __restrict__ W2t,
                 const float* __restrict__ b2, const float* __restrict__ W3,
                 const float* __restrict__ b3, const float* __restrict__ sparse,
                 float* __restrict__ out_dense, float* __restrict__ out_sparse,
                 float* __restrict__ out_final){
    __shared__ __align__(16) short lw[73728];        // 147,456 B  W2 bf16 (16x16x32 frag order)
    __shared__ __align__(16) short lbw[6144];        //  12,288 B  Bws slice [16 docs][384] bf16
    __shared__ __align__(16) float lcd[768];         //   3,072 B  [0..383]=W1c, [384..767]=W1d
    const int tid = threadIdx.x, bb = blockIdx.x;
    const int r0 = bb*16;
    const int lane = tid & 63, w = tid >> 6;

    if (w < 4){
        // ---- Bws GEMM + dense for this block's 16 docs (pre1-verified, inline f32->bf16)
        const int cl = lane & 15, quad = lane >> 4, tq = w & 1;
        const float* ap = doc + (r0+cl)*384 + quad*8;
        const float* qp = query + (tq*16 + cl)*384 + quad*8;
        const short* wp = W1t + 147456 + (w*6)*512 + lane*8;   // W1b half

        f32x4 acc[6];
        #pragma unroll
        for (int t=0;t<6;t++) acc[t] = (f32x4){0.f,0.f,0.f,0.f};
        f32x4 accd = (f32x4){0.f,0.f,0.f,0.f};

        f32x4 a0c = *(const f32x4*)(ap),  a1c = *(const f32x4*)(ap+4);
        f32x4 q0c = *(const f32x4*)(qp),  q1c = *(const f32x4*)(qp+4);
        bf16x8 b_c[6];
        #pragma unroll
        for (int tt=0;tt<6;tt++) b_c[tt] = *(const bf16x8*)(wp + tt*512);

        #pragma unroll 1
        for (int s=0;s<12;s++){
            const int sn = (s < 11) ? s+1 : 0;       // dummy wrap on last iter
            const f32x4 a0n = *(const f32x4*)(ap + sn*32);
            const f32x4 a1n = *(const f32x4*)(ap + sn*32 + 4);
            const f32x4 q0n = *(const f32x4*)(qp + sn*32);
            const f32x4 q1n = *(const f32x4*)(qp + sn*32 + 4);
            bf16x8 b_n[6];
            #pragma unroll
            for (int tt=0;tt<6;tt++) b_n[tt] = *(const bf16x8*)(wp + sn*12288 + tt*512);

            u32x4 ua, uq;
            ua[0] = cvt2(a0c[0],a0c[1]); ua[1] = cvt2(a0c[2],a0c[3]);
            ua[2] = cvt2(a1c[0],a1c[1]); ua[3] = cvt2(a1c[2],a1c[3]);
            uq[0] = cvt2(q0c[0],q0c[1]); uq[1] = cvt2(q0c[2],q0c[3]);
            uq[2] = cvt2(q1c[0],q1c[1]); uq[3] = cvt2(q1c[2],q1c[3]);
            const bf16x8 af = __builtin_bit_cast(bf16x8, ua);
            const bf16x8 qf = __builtin_bit_cast(bf16x8, uq);

            #pragma unroll
            for (int tt=0;tt<6;tt++)
                acc[tt] = __builtin_amdgcn_mfma_f32_16x16x32_bf16(af, b_c[tt], acc[tt], 0, 0, 0);
            accd = __builtin_amdgcn_mfma_f32_16x16x32_bf16(af, qf, accd, 0, 0, 0);

            a0c = a0n; a1c = a1n; q0c = q0n; q1c = q1n;
            #pragma unroll
            for (int tt=0;tt<6;tt++) b_c[tt] = b_n[tt];
        }

        // Bws slice -> LDS: doc_local = quad*4+r, col = (w*6+tt)*16+cl
        #pragma unroll
        for (int tt=0;tt<6;tt++){
            const int col = (w*6+tt)*16 + cl;
            #pragma unroll
            for (int r=0;r<4;r++)
                lbw[(quad*4 + r)*384 + col] = f2bf(acc[tt][r]);
        }
        // dense store (waves 0,1 only; waves 2,3 computed duplicates for uniformity)
        if (w < 2){
            #pragma unroll
            for (int r=0;r<4;r++)
                out_dense[(tq*16 + cl)*4096 + r0 + quad*4 + r] = accd[r];
        }
    } else {
        // ---- staging: lw (waves 4..15, 12 chunks each), lcd, sparse copy
        #pragma unroll
        for (int i=0;i<12;i++){
            const int c = (w-4)*64 + lane + i*768;   // < 9216
            *(f32x4*)(lw + c*8) = *(const f32x4*)(W2t + c*8);
        }
        if (tid >= 256 && tid < 448){
            const int t = tid - 256;
            *(f32x4*)(lcd + t*4) = *(const f32x4*)(W1cdf + t*4);
        }
        if (tid >= 512 && tid < 640){
            const int idx = tid - 512;
            const int qq = idx >> 2, c4 = idx & 3;
            *(f32x4*)(out_sparse + qq*4096 + r0 + c4*4) =
                *(const f32x4*)(sparse + qq*4096 + r0 + c4*4);
        }
    }
    __syncthreads();    // drains vmcnt -> dense stores visible via L2; LDS complete

    // ---- MLP (r4/r5 structure verbatim; bw from LDS)
    const int colslot = w >> 1, mhalf = w & 1;
    const int cl = lane & 15, g = lane >> 4;
    const int mrow = mhalf*16 + cl;                  // q-row of this lane's A-frag
    const int k8 = g*8;                              // k-offset within a K=32 step
    const float b3v = b3[0];
    const int dcol0 = r0 + colslot;

    #pragma unroll 1
    for (int t4=0; t4<2; t4++){
        const int dcol = dcol0 + t4*8;
        const float dsv = out_dense[mrow*4096 + dcol];
        const float ssv = sparse[mrow*4096 + dcol];
        const f32x2 dsv2 = {dsv, dsv}, ssv2 = {ssv, ssv};

        f32x4 acc[12];
        #pragma unroll
        for (int t=0;t<12;t++) acc[t] = (f32x4){0.f,0.f,0.f,0.f};

        const short* bp = lbw + (dcol - r0)*384;     // LDS Bws row
        const float* ap = Aq + mrow*384;

        // depth-2 prefetch (slot C = current step)
        bf16x8 bwC = *(const bf16x8*)(bp + k8);
        f32x4  aC0 = *(const f32x4*)(ap + k8);
        f32x4  aC1 = *(const f32x4*)(ap + k8 + 4);

        #pragma unroll 1
        for (int s=0; s<12; s++){
            const int kn = (s < 11) ? (s+1)*32 + k8 : k8;    // dummy wrap at tail
            const bf16x8 bwN = *(const bf16x8*)(bp + kn);
            const f32x4  aN0 = *(const f32x4*)(ap + kn);
            const f32x4  aN1 = *(const f32x4*)(ap + kn + 4);

            const int kf = s*32 + k8;
            const f32x4 wcA = *(const f32x4*)(lcd + kf);
            const f32x4 wcB = *(const f32x4*)(lcd + kf + 4);
            const f32x4 wdA = *(const f32x4*)(lcd + 384 + kf);
            const f32x4 wdB = *(const f32x4*)(lcd + 384 + kf + 4);

            u32x4 frw;
            { f32x2 h = {aC0[0] + bf2f(bwC[0]), aC0[1] + bf2f(bwC[1])};
              h += dsv2 * (f32x2){wcA[0],wcA[1]}; h += ssv2 * (f32x2){wdA[0],wdA[1]};
              frw[0] = cvt2(fmaxf(h[0],0.f), fmaxf(h[1],0.f)); }
            { f32x2 h = {aC0[2] + bf2f(bwC[2]), aC0[3] + bf2f(bwC[3])};
              h += dsv2 * (f32x2){wcA[2],wcA[3]}; h += ssv2 * (f32x2){wdA[2],wdA[3]};
              frw[1] = cvt2(fmaxf(h[0],0.f), fmaxf(h[1],0.f)); }
            { f32x2 h = {aC1[0] + bf2f(bwC[4]), aC1[1] + bf2f(bwC[5])};
              h += dsv2 * (f32x2){wcB[0],wcB[1]}; h += ssv2 * (f32x2){wdB[0],wdB[1]};
              frw[2] = cvt2(fmaxf(h[0],0.f), fmaxf(h[1],0.f)); }
            { f32x2 h = {aC1[2] + bf2f(bwC[6]), aC1[3] + bf2f(bwC[7])};
              h += dsv2 * (f32x2){wcB[2],wcB[3]}; h += ssv2 * (f32x2){wdB[2],wdB[3]};
              frw[3] = cvt2(fmaxf(h[0],0.f), fmaxf(h[1],0.f)); }
            const bf16x8 fr = __builtin_bit_cast(bf16x8, frw);

            // 12 n-tiles in groups of 3 (limits live bfr regs to 12)
            const short* lp = lw + s*6144 + lane*8;          // s*12*512 shorts
            #pragma unroll
            for (int tg=0; tg<4; tg++){
                const bf16x8 f0 = *(const bf16x8*)(lp + (tg*3+0)*512);
                const bf16x8 f1 = *(const bf16x8*)(lp + (tg*3+1)*512);
                const bf16x8 f2 = *(const bf16x8*)(lp + (tg*3+2)*512);
                acc[tg*3+0] = __builtin_amdgcn_mfma_f32_16x16x32_bf16(fr, f0, acc[tg*3+0], 0, 0, 0);
                acc[tg*3+1] = __builtin_amdgcn_mfma_f32_16x16x32_bf16(fr, f1, acc[tg*3+1], 0, 0, 0);
                acc[tg*3+2] = __builtin_amdgcn_mfma_f32_16x16x32_bf16(fr, f2, acc[tg*3+2], 0, 0, 0);
            }
            bwC = bwN; aC0 = aN0; aC1 = aN1;
        }

        // layer 3: this lane covers n = t*16+cl for rows g*4+r (+mhalf*16)
        float p0=0.f, p1=0.f, p2=0.f, p3=0.f;
        #pragma unroll
        for (int t=0;t<12;t++){
            const int n = t*16 + cl;
            const float b2v = b2[n];
            const float w3v = W3[n];
            p0 += fmaxf(acc[t][0] + b2v, 0.0f) * w3v;
            p1 += fmaxf(acc[t][1] + b2v, 0.0f) * w3v;
            p2 += fmaxf(acc[t][2] + b2v, 0.0f) * w3v;
            p3 += fmaxf(acc[t][3] + b2v, 0.0f) * w3v;
        }
        // reduce over the 16 lanes of this g-group (masks 1..8 stay within the group)
        #pragma unroll
        for (int mask=1; mask<16; mask<<=1){
            p0 += __shfl_xor(p0, mask);
            p1 += __shfl_xor(p1, mask);
            p2 += __shfl_xor(p2, mask);
            p3 += __shfl_xor(p3, mask);
        }
        // lane cl<4 writes row mhalf*16 + g*4 + cl (static cndmask chain)
        float myp = p0;
        myp = (cl==1) ? p1 : myp;
        myp = (cl==2) ? p2 : myp;
        myp = (cl==3) ? p3 : myp;
        if (cl < 4){
            const int row = mhalf*16 + g*4 + cl;
            const float logit = myp + b3v;
            const float wgt = 1.0f/(1.0f + __expf(-logit));
            const float dd = out_dense[row*4096 + dcol];
            const float ss = sparse[row*4096 + dcol];
            out_final[row*4096 + dcol] = wgt*dd + (1.0f - wgt)*ss;
        }
    }
}

// ---------------------------------------------------------------- launch
extern "C" void kernel_launch(void* const* d_in, const int* in_sizes, int n_in,
                              void* d_out, int out_size, void* d_ws, size_t ws_size,
                              hipStream_t stream){
    const float* query  = (const float*)d_in[0];
    const float* doc    = (const float*)d_in[1];
    const float* sparse = (const float*)d_in[2];
    const float* W1     = (const float*)d_in[3];
    const float* b1     = (const float*)d_in[4];
    const float* W2     = (const float*)d_in[5];
    const float* b2     = (const float*)d_in[6];
    const float* W3     = (const float*)d_in[7];
    const float* b3     = (const float*)d_in[8];

    float* out_final  = (float*)d_out;                 // [32,4096]
    float* out_dense  = (float*)d_out + 131072;        // [32,4096]
    float* out_sparse = (float*)d_out + 262144;        // [32,4096]

    // workspace layout (16B-aligned), total 789,504 B
    short* W1t   = (short*)d_ws;                                  //   589,824 B  (bf16 tiled W1a+W1b)
    short* W2t   = (short*)((char*)d_ws + 589824);                //   147,456 B  (bf16 tiled W2)
    float* W1cdf = (float*)((char*)d_ws + 737280);                //     3,072 B  (f32  [768])
    float* Aq    = (float*)((char*)d_ws + 740352);                //    49,152 B  (f32  [32][384])

    hipLaunchKernelGGL(prep_kernel, dim3(125), dim3(256), 0, stream,
                       query, W1, b1, W2, W1t, W1cdf, W2t, Aq);
    hipLaunchKernelGGL(main_kernel, dim3(256), dim3(1024), 0, stream,
                       doc, query, Aq, W1t, W1cdf, W2t, b2, W3, b3, sparse,
                       out_dense, out_sparse, out_final);
}